// Round 4
// baseline (192.471 us; speedup 1.0000x reference)
//
#include <hip/hip_runtime.h>

// MHSA fwd MFMA bf16: B=8, N=1024, D=1024, H=16, DK=64. fp32 in/out, bf16 compute.
// Round 4: GEMMs -> 256x128 8-wave 4-phase schedule (T2 swizzle + T3 phases +
// T4 counted vmcnt + T5 setprio). Attention unchanged from round 3.

typedef __attribute__((ext_vector_type(8))) short bf16x8;
typedef __attribute__((ext_vector_type(4))) float f32x4;

#define GLOAD_LDS16(gp, lp)                                                              \
  __builtin_amdgcn_global_load_lds((const __attribute__((address_space(1))) void*)(gp),  \
                                   (__attribute__((address_space(3))) void*)(lp), 16, 0, 0)

__device__ __forceinline__ unsigned short f2bf(float f) {
  unsigned int u = __float_as_uint(f);
  u += 0x7fffu + ((u >> 16) & 1u);          // RNE
  return (unsigned short)(u >> 16);
}

// ---------------------------------------------------------------------------
__global__ __launch_bounds__(256) void cast_f32_to_bf16(
    const float* __restrict__ in, unsigned short* __restrict__ out, int n4) {
  int stride = gridDim.x * blockDim.x;
  for (int i = blockIdx.x * blockDim.x + threadIdx.x; i < n4; i += stride) {
    float4 v = reinterpret_cast<const float4*>(in)[i];
    ushort4 o;
    o.x = f2bf(v.x); o.y = f2bf(v.y); o.z = f2bf(v.z); o.w = f2bf(v.w);
    reinterpret_cast<ushort4*>(out)[i] = o;
  }
}

// W [R][C] f32 -> Wt [C][R] bf16
__global__ __launch_bounds__(256) void transpose_cast(
    const float* __restrict__ W, unsigned short* __restrict__ Wt, int R, int C) {
  __shared__ float tile[32][33];
  int tx = threadIdx.x & 31, ty = threadIdx.x >> 5;
  int c0 = blockIdx.x * 32, r0 = blockIdx.y * 32;
  #pragma unroll
  for (int i = 0; i < 4; i++) {
    int r = r0 + ty + i * 8;
    tile[ty + i * 8][tx] = W[(size_t)r * C + c0 + tx];
  }
  __syncthreads();
  #pragma unroll
  for (int i = 0; i < 4; i++) {
    int c = c0 + ty + i * 8;
    Wt[(size_t)c * R + r0 + tx] = f2bf(tile[tx][ty + i * 8]);
  }
}

// ---------------------------------------------------------------------------
// GEMM 256x128, BK=64, 512 thr (8 waves as 4M x 2N; 64x64 per wave, 4x4 frags).
// K=1024 -> 16 K-tiles. Per tile: 4 phases x 8 MFMA, dbuf LDS, counted vmcnt,
// raw barriers, setprio. A [8192][1024] bf16; Bt [N][1024] bf16 (B^T).
// MODE 0: qkv scatter (Q pre-scaled 0.125, V transposed per head). MODE 1: f32.
// ---------------------------------------------------------------------------
template <int MODE>
__global__ __launch_bounds__(512) void gemm256(
    const unsigned short* __restrict__ A, const unsigned short* __restrict__ Bt,
    const float* __restrict__ bias, unsigned short* __restrict__ qkv_out,
    float* __restrict__ Cout) {
  __shared__ __align__(16) unsigned short As[2][256 * 64];   // [row][k] swz
  __shared__ __align__(16) unsigned short Bs[2][128 * 64];   // [col][k] swz
  const int t = threadIdx.x;
  const int lane = t & 63, wid = t >> 6;
  const int lr = lane & 15, g = lane >> 4;
  const int row0 = blockIdx.y * 256, col0 = blockIdx.x * 128;
  const int wr = wid >> 1, wc = wid & 1;
  const int srow = t >> 3, sch = t & 7;     // staging: 512 thr x 16B = 64 rows

  auto stA = [&](int buf, int kt, int j) {  // j=0..3: rows j*64..j*64+63
    int row = j * 64 + srow;
    int ch = sch ^ (row & 7);               // source pre-swizzle
    GLOAD_LDS16(A + (size_t)(row0 + row) * 1024 + kt * 64 + ch * 8,
                (char*)&As[buf][0] + j * 8192 + t * 16);
  };
  auto stB = [&](int buf, int kt, int j) {  // j=0..1
    int row = j * 64 + srow;
    int ch = sch ^ (row & 7);
    GLOAD_LDS16(Bt + (size_t)(col0 + row) * 1024 + kt * 64 + ch * 8,
                (char*)&Bs[buf][0] + j * 8192 + t * 16);
  };
  auto rdA = [&](int buf, int c, int m) -> bf16x8 {
    int r = wr * 64 + m * 16 + lr;
    return *(const bf16x8*)((const char*)&As[buf][0] + r * 128 +
                            ((c * 64 + g * 16) ^ ((r & 7) << 4)));
  };
  auto rdB = [&](int buf, int c, int n) -> bf16x8 {
    int r = wc * 64 + n * 16 + lr;
    return *(const bf16x8*)((const char*)&Bs[buf][0] + r * 128 +
                            ((c * 64 + g * 16) ^ ((r & 7) << 4)));
  };

  f32x4 acc[4][4] = {};

  // prologue: stage tile 0 fully (6 loads)
  stA(0, 0, 0); stA(0, 0, 1); stA(0, 0, 2); stA(0, 0, 3);
  stB(0, 0, 0); stB(0, 0, 1);

  for (int kt = 0; kt < 16; kt++) {
    const int buf = kt & 1;
    const bool pf = (kt + 1 < 16);
    // issue first 2 prefetch loads, then counted wait: tile-kt loads landed,
    // prefetch stays in flight (never vmcnt(0) mid-loop).
    if (pf) {
      stA(buf ^ 1, kt + 1, 0); stA(buf ^ 1, kt + 1, 1);
      asm volatile("s_waitcnt vmcnt(2)" ::: "memory");
    } else {
      asm volatile("s_waitcnt vmcnt(0)" ::: "memory");
    }
    __builtin_amdgcn_s_barrier();   // all waves' tile-kt loads landed

    bf16x8 b0[4], b1[4], afr[2];

    // ---- phase 0: c=0, m=0..1
    #pragma unroll
    for (int n = 0; n < 4; n++) b0[n] = rdB(buf, 0, n);
    afr[0] = rdA(buf, 0, 0); afr[1] = rdA(buf, 0, 1);
    if (pf) { stA(buf ^ 1, kt + 1, 2); stA(buf ^ 1, kt + 1, 3); }
    __builtin_amdgcn_s_barrier();
    __builtin_amdgcn_s_setprio(1);
    #pragma unroll
    for (int m = 0; m < 2; m++)
      #pragma unroll
      for (int n = 0; n < 4; n++)
        acc[m][n] = __builtin_amdgcn_mfma_f32_16x16x32_bf16(afr[m], b0[n], acc[m][n], 0, 0, 0);
    __builtin_amdgcn_s_setprio(0);
    __builtin_amdgcn_s_barrier();

    // ---- phase 1: c=0, m=2..3
    afr[0] = rdA(buf, 0, 2); afr[1] = rdA(buf, 0, 3);
    if (pf) { stB(buf ^ 1, kt + 1, 0); stB(buf ^ 1, kt + 1, 1); }
    __builtin_amdgcn_s_barrier();
    __builtin_amdgcn_s_setprio(1);
    #pragma unroll
    for (int m = 0; m < 2; m++)
      #pragma unroll
      for (int n = 0; n < 4; n++)
        acc[2 + m][n] = __builtin_amdgcn_mfma_f32_16x16x32_bf16(afr[m], b0[n], acc[2 + m][n], 0, 0, 0);
    __builtin_amdgcn_s_setprio(0);
    __builtin_amdgcn_s_barrier();

    // ---- phase 2: c=1, m=0..1
    #pragma unroll
    for (int n = 0; n < 4; n++) b1[n] = rdB(buf, 1, n);
    afr[0] = rdA(buf, 1, 0); afr[1] = rdA(buf, 1, 1);
    __builtin_amdgcn_s_barrier();
    __builtin_amdgcn_s_setprio(1);
    #pragma unroll
    for (int m = 0; m < 2; m++)
      #pragma unroll
      for (int n = 0; n < 4; n++)
        acc[m][n] = __builtin_amdgcn_mfma_f32_16x16x32_bf16(afr[m], b1[n], acc[m][n], 0, 0, 0);
    __builtin_amdgcn_s_setprio(0);
    __builtin_amdgcn_s_barrier();

    // ---- phase 3: c=1, m=2..3
    afr[0] = rdA(buf, 1, 2); afr[1] = rdA(buf, 1, 3);
    __builtin_amdgcn_s_barrier();
    __builtin_amdgcn_s_setprio(1);
    #pragma unroll
    for (int m = 0; m < 2; m++)
      #pragma unroll
      for (int n = 0; n < 4; n++)
        acc[2 + m][n] = __builtin_amdgcn_mfma_f32_16x16x32_bf16(afr[m], b1[n], acc[2 + m][n], 0, 0, 0);
    __builtin_amdgcn_s_setprio(0);
    asm volatile("" ::: "memory");
    __builtin_amdgcn_s_barrier();   // end of tile: buf reusable for kt+2 staging
  }

  // ---------------- epilogue ----------------
  if (MODE == 0) {
    const int which = col0 >> 10;   // block-uniform (1024 % 128 == 0)
    if (which == 2) {
      // V^T: vt[bh][dk][n]; 4 consecutive n pack to ushort4
      #pragma unroll
      for (int m = 0; m < 4; m++) {
        int row = row0 + wr * 64 + m * 16 + g * 4;
        int bb = row >> 10, nn = row & 1023;
        #pragma unroll
        for (int n = 0; n < 4; n++) {
          int col = col0 + wc * 64 + n * 16 + lr;
          int cc = col & 1023;
          int h = cc >> 6, dk = cc & 63;
          float bv = bias[col];
          ushort4 w;
          w.x = f2bf(acc[m][n][0] + bv);
          w.y = f2bf(acc[m][n][1] + bv);
          w.z = f2bf(acc[m][n][2] + bv);
          w.w = f2bf(acc[m][n][3] + bv);
          size_t idx = ((size_t)2 << 23) + (((size_t)(bb * 16 + h)) << 16) +
                       (size_t)dk * 1024 + nn;
          *(ushort4*)(qkv_out + idx) = w;
        }
      }
    } else {
      #pragma unroll
      for (int m = 0; m < 4; m++) {
        #pragma unroll
        for (int n = 0; n < 4; n++) {
          int col = col0 + wc * 64 + n * 16 + lr;
          int cc = col & 1023;
          int h = cc >> 6, dk = cc & 63;
          #pragma unroll
          for (int r = 0; r < 4; r++) {
            int row = row0 + wr * 64 + m * 16 + g * 4 + r;
            int bb = row >> 10, nn = row & 1023;
            float v = acc[m][n][r] + bias[col];
            if (which == 0) v *= 0.125f;   // fold 1/sqrt(dk) into Q
            size_t idx = ((size_t)which << 23) +
                         (((size_t)((bb * 16 + h) * 1024 + nn)) << 6) + dk;
            qkv_out[idx] = f2bf(v);
          }
        }
      }
    }
  } else {
    #pragma unroll
    for (int m = 0; m < 4; m++) {
      #pragma unroll
      for (int n = 0; n < 4; n++) {
        int col = col0 + wc * 64 + n * 16 + lr;
        #pragma unroll
        for (int r = 0; r < 4; r++) {
          int row = row0 + wr * 64 + m * 16 + g * 4 + r;
          Cout[(size_t)row * 1024 + col] = acc[m][n][r] + bias[col];
        }
      }
    }
  }
}

// ---------------------------------------------------------------------------
// Attention (unchanged from round 3): 8 waves, QBLK=128, KVBLK=64, dbuf
// prefetch, V pre-transposed by GEMM1, setprio, XCD swizzle.
// ---------------------------------------------------------------------------
__global__ __launch_bounds__(512) void attn_mfma(
    const unsigned short* __restrict__ qkv, unsigned short* __restrict__ attn_out) {
  __shared__ __align__(16) unsigned short K_lds[2][64 * 64];   // [k][d] swz
  __shared__ __align__(16) unsigned short V_lds[2][64 * 64];   // [d][k] swz
  __shared__ __align__(16) unsigned short P_lds[128 * 64];     // [q][k] swz

  const int bid = ((blockIdx.x & 7) << 7) + (blockIdx.x >> 3);
  const int bh = bid >> 3, qt = bid & 7;
  const unsigned short* Qp = qkv + ((size_t)bh << 16);
  const unsigned short* Kp = qkv + (1u << 23) + ((size_t)bh << 16);
  const unsigned short* Vt = qkv + (2u << 23) + ((size_t)bh << 16);  // [dk][n]

  const int t = threadIdx.x;
  const int lane = t & 63, wid = t >> 6;
  const int lr = lane & 15, g = lane >> 4;

  bf16x8 qf[2];
  {
    int qrow = qt * 128 + wid * 16 + lr;
    qf[0] = *(const bf16x8*)(Qp + (size_t)qrow * 64 + g * 8);
    qf[1] = *(const bf16x8*)(Qp + (size_t)qrow * 64 + 32 + g * 8);
  }

  const int srow = t >> 3;
  const int sch  = (t & 7) ^ (srow & 7);
  const int so   = t * 16;

  auto stage = [&](int buf, int kt) {
    GLOAD_LDS16(Kp + (size_t)(kt * 64 + srow) * 64 + sch * 8, (char*)&K_lds[buf][0] + so);
    GLOAD_LDS16(Vt + (size_t)srow * 1024 + kt * 64 + sch * 8, (char*)&V_lds[buf][0] + so);
  };

  f32x4 o_acc[4] = {};
  float den[4] = {0.f, 0.f, 0.f, 0.f};

  stage(0, 0);
  __syncthreads();
  int buf = 0;
  for (int kt = 0; kt < 16; kt++) {
    if (kt + 1 < 16) stage(buf ^ 1, kt + 1);

    f32x4 s4[4] = {};
    __builtin_amdgcn_s_setprio(1);
    #pragma unroll
    for (int ks = 0; ks < 4; ks++) {
      int krow = ks * 16 + lr;
      #pragma unroll
      for (int c = 0; c < 2; c++) {
        bf16x8 kf = *(const bf16x8*)((char*)&K_lds[buf][0] + krow * 128 +
                                     ((c * 64 + g * 16) ^ ((krow & 7) << 4)));
        s4[ks] = __builtin_amdgcn_mfma_f32_16x16x32_bf16(qf[c], kf, s4[ks], 0, 0, 0);
      }
    }
    __builtin_amdgcn_s_setprio(0);

    #pragma unroll
    for (int ks = 0; ks < 4; ks++) {
      #pragma unroll
      for (int r = 0; r < 4; r++) {
        float e = __expf(s4[ks][r]);
        den[r] += e;
        int q = wid * 16 + g * 4 + r;
        *(unsigned short*)((char*)P_lds + q * 128 +
                           (((ks * 16 + lr) * 2) ^ ((q & 7) << 4))) = f2bf(e);
      }
    }

    bf16x8 pa[2];
    {
      int q = wid * 16 + lr;
      #pragma unroll
      for (int c = 0; c < 2; c++)
        pa[c] = *(const bf16x8*)((char*)P_lds + q * 128 +
                                 ((c * 64 + g * 16) ^ ((q & 7) << 4)));
    }
    __builtin_amdgcn_s_setprio(1);
    #pragma unroll
    for (int ds_ = 0; ds_ < 4; ds_++) {
      int drow = ds_ * 16 + lr;
      #pragma unroll
      for (int c = 0; c < 2; c++) {
        bf16x8 vf = *(const bf16x8*)((char*)&V_lds[buf][0] + drow * 128 +
                                     ((c * 64 + g * 16) ^ ((drow & 7) << 4)));
        o_acc[ds_] = __builtin_amdgcn_mfma_f32_16x16x32_bf16(pa[c], vf, o_acc[ds_], 0, 0, 0);
      }
    }
    __builtin_amdgcn_s_setprio(0);
    __syncthreads();
    buf ^= 1;
  }

  #pragma unroll
  for (int r = 0; r < 4; r++) {
    den[r] += __shfl_xor(den[r], 1, 64);
    den[r] += __shfl_xor(den[r], 2, 64);
    den[r] += __shfl_xor(den[r], 4, 64);
    den[r] += __shfl_xor(den[r], 8, 64);
  }

  const int bb = bh >> 4, h = bh & 15;
  #pragma unroll
  for (int ds_ = 0; ds_ < 4; ds_++) {
    #pragma unroll
    for (int r = 0; r < 4; r++) {
      int q = qt * 128 + wid * 16 + g * 4 + r;
      int d = h * 64 + ds_ * 16 + lr;
      attn_out[((size_t)(bb * 1024 + q)) * 1024 + d] = f2bf(o_acc[ds_][r] / den[r]);
    }
  }
}

// ---------------------------------------------------------------------------
extern "C" void kernel_launch(void* const* d_in, const int* in_sizes, int n_in,
                              void* d_out, int out_size, void* d_ws, size_t ws_size,
                              hipStream_t stream) {
  const float* x     = (const float*)d_in[0];
  const float* W_qkv = (const float*)d_in[1];
  const float* b_qkv = (const float*)d_in[2];
  const float* W_o   = (const float*)d_in[3];
  const float* b_o   = (const float*)d_in[4];
  float* out = (float*)d_out;

  unsigned short* ws      = (unsigned short*)d_ws;
  unsigned short* x_bf    = ws;                     //  8388608
  unsigned short* wqkv_t  = x_bf + 8388608;         //  3145728
  unsigned short* wo_t    = wqkv_t + 3145728;       //  1048576
  unsigned short* qkv     = wo_t + 1048576;         // 25165824 (3 x 2^23)
  unsigned short* attn_o  = qkv + 25165824;         //  8388608

  cast_f32_to_bf16<<<2048, 256, 0, stream>>>(x, x_bf, 8388608 / 4);
  transpose_cast<<<dim3(96, 32), 256, 0, stream>>>(W_qkv, wqkv_t, 1024, 3072);
  transpose_cast<<<dim3(32, 32), 256, 0, stream>>>(W_o, wo_t, 1024, 1024);

  gemm256<0><<<dim3(24, 32), 512, 0, stream>>>(x_bf, wqkv_t, b_qkv, qkv, nullptr);
  attn_mfma<<<1024, 512, 0, stream>>>(qkv, attn_o);
  gemm256<1><<<dim3(8, 32), 512, 0, stream>>>(attn_o, wo_t, b_o, nullptr, out);
}

// Round 5
// 184.177 us; speedup vs baseline: 1.0450x; 1.0450x over previous
//
#include <hip/hip_runtime.h>

// MHSA fwd MFMA bf16: B=8, N=1024, D=1024, H=16, DK=64. fp32 in/out, bf16 compute.
// Round 5: GEMMs -> 128x256 (BM x BN), BK=64, 8 waves (2M x 4N, 64x64/wave),
// 2 phases x 16 MFMA per K-tile, counted vmcnt, per-phase barrier pairs,
// setprio, XCD-swizzled grids. Attention unchanged from round 3.

typedef __attribute__((ext_vector_type(8))) short bf16x8;
typedef __attribute__((ext_vector_type(4))) float f32x4;

#define GLOAD_LDS16(gp, lp)                                                              \
  __builtin_amdgcn_global_load_lds((const __attribute__((address_space(1))) void*)(gp),  \
                                   (__attribute__((address_space(3))) void*)(lp), 16, 0, 0)

__device__ __forceinline__ unsigned short f2bf(float f) {
  unsigned int u = __float_as_uint(f);
  u += 0x7fffu + ((u >> 16) & 1u);          // RNE
  return (unsigned short)(u >> 16);
}

// ---------------------------------------------------------------------------
__global__ __launch_bounds__(256) void cast_f32_to_bf16(
    const float* __restrict__ in, unsigned short* __restrict__ out, int n4) {
  int stride = gridDim.x * blockDim.x;
  for (int i = blockIdx.x * blockDim.x + threadIdx.x; i < n4; i += stride) {
    float4 v = reinterpret_cast<const float4*>(in)[i];
    ushort4 o;
    o.x = f2bf(v.x); o.y = f2bf(v.y); o.z = f2bf(v.z); o.w = f2bf(v.w);
    reinterpret_cast<ushort4*>(out)[i] = o;
  }
}

// W [R][C] f32 -> Wt [C][R] bf16
__global__ __launch_bounds__(256) void transpose_cast(
    const float* __restrict__ W, unsigned short* __restrict__ Wt, int R, int C) {
  __shared__ float tile[32][33];
  int tx = threadIdx.x & 31, ty = threadIdx.x >> 5;
  int c0 = blockIdx.x * 32, r0 = blockIdx.y * 32;
  #pragma unroll
  for (int i = 0; i < 4; i++) {
    int r = r0 + ty + i * 8;
    tile[ty + i * 8][tx] = W[(size_t)r * C + c0 + tx];
  }
  __syncthreads();
  #pragma unroll
  for (int i = 0; i < 4; i++) {
    int c = c0 + ty + i * 8;
    Wt[(size_t)c * R + r0 + tx] = f2bf(tile[tx][ty + i * 8]);
  }
}

// ---------------------------------------------------------------------------
// GEMM 128x256, BK=64, 512 thr (8 waves = 2M x 4N; 64x64 per wave, 4x4 frags).
// K=1024 -> 16 K-tiles. Per tile: 2 phases x 16 MFMA, dbuf LDS, counted vmcnt
// at tile top only, per-phase {reads||stage -> barrier -> lgkm0 -> MFMA ->
// barrier}. A [8192][1024] bf16; Bt [N][1024] bf16 (B^T).
// MODE 0: qkv scatter (Q pre-scaled 0.125, V transposed per head). MODE 1: f32.
// ---------------------------------------------------------------------------
template <int MODE>
__global__ __launch_bounds__(512) void gemm256(
    const unsigned short* __restrict__ A, const unsigned short* __restrict__ Bt,
    const float* __restrict__ bias, unsigned short* __restrict__ qkv_out,
    float* __restrict__ Cout) {
  __shared__ __align__(16) unsigned short As[2][128 * 64];   // 32 KB, [row][k] swz
  __shared__ __align__(16) unsigned short Bs[2][256 * 64];   // 64 KB, [col][k] swz
  const int t = threadIdx.x;
  const int lane = t & 63, wid = t >> 6;
  const int lr = lane & 15, g = lane >> 4;
  const int wm = wid >> 2, wn = wid & 3;

  // XCD-aware bijective swizzle (grid counts divisible by 8)
  const int nwg = gridDim.x * gridDim.y;
  const int id = blockIdx.x + gridDim.x * blockIdx.y;
  const int sw = (id & 7) * (nwg >> 3) + (id >> 3);
  const int bx = sw % gridDim.x, by = sw / gridDim.x;
  const int row0 = by * 128, col0 = bx * 256;

  const int srow = t >> 3, sch = t & 7;     // staging: 512 thr x 16B = 64 rows

  auto stA = [&](int buf, int kt, int j) {  // j=0..1: rows j*64..j*64+63
    int row = j * 64 + srow;
    int ch = sch ^ (row & 7);               // source pre-swizzle
    GLOAD_LDS16(A + (size_t)(row0 + row) * 1024 + kt * 64 + ch * 8,
                (char*)&As[buf][0] + j * 8192 + t * 16);
  };
  auto stB = [&](int buf, int kt, int j) {  // j=0..3: cols j*64..j*64+63
    int row = j * 64 + srow;
    int ch = sch ^ (row & 7);
    GLOAD_LDS16(Bt + (size_t)(col0 + row) * 1024 + kt * 64 + ch * 8,
                (char*)&Bs[buf][0] + j * 8192 + t * 16);
  };
  auto rdA = [&](int buf, int c, int m) -> bf16x8 {
    int r = wm * 64 + m * 16 + lr;
    return *(const bf16x8*)((const char*)&As[buf][0] + r * 128 +
                            ((c * 64 + g * 16) ^ ((r & 7) << 4)));
  };
  auto rdB = [&](int buf, int c, int n) -> bf16x8 {
    int r = wn * 64 + n * 16 + lr;
    return *(const bf16x8*)((const char*)&Bs[buf][0] + r * 128 +
                            ((c * 64 + g * 16) ^ ((r & 7) << 4)));
  };

  f32x4 acc[4][4] = {};

  // prologue: stage tile 0 fully (6 ops), drain once
  stA(0, 0, 0); stA(0, 0, 1);
  stB(0, 0, 0); stB(0, 0, 1); stB(0, 0, 2); stB(0, 0, 3);
  asm volatile("s_waitcnt vmcnt(0)" ::: "memory");
  __builtin_amdgcn_s_barrier();

  for (int kt = 0; kt < 16; kt++) {
    const int buf = kt & 1;
    const bool pf = (kt + 1 < 16);
    if (kt > 0) {
      // tile kt's 6 loads are the oldest outstanding; issue 2 of kt+1 first,
      // then counted wait: vmcnt(2) -> kt landed, 2 prefetch in flight.
      if (pf) {
        stA(buf ^ 1, kt + 1, 0); stA(buf ^ 1, kt + 1, 1);
        asm volatile("s_waitcnt vmcnt(2)" ::: "memory");
      } else {
        asm volatile("s_waitcnt vmcnt(0)" ::: "memory");
      }
      __builtin_amdgcn_s_barrier();
    } else if (pf) {
      stA(buf ^ 1, kt + 1, 0); stA(buf ^ 1, kt + 1, 1);
    }

    // ---- phase 0: k-step 0 ----
    bf16x8 a0[4], b0[4];
    #pragma unroll
    for (int m = 0; m < 4; m++) a0[m] = rdA(buf, 0, m);
    #pragma unroll
    for (int n = 0; n < 4; n++) b0[n] = rdB(buf, 0, n);
    if (pf) { stB(buf ^ 1, kt + 1, 0); stB(buf ^ 1, kt + 1, 1); }
    __builtin_amdgcn_s_barrier();
    asm volatile("s_waitcnt lgkmcnt(0)" ::: "memory");
    __builtin_amdgcn_sched_barrier(0);
    __builtin_amdgcn_s_setprio(1);
    #pragma unroll
    for (int m = 0; m < 4; m++)
      #pragma unroll
      for (int n = 0; n < 4; n++)
        acc[m][n] = __builtin_amdgcn_mfma_f32_16x16x32_bf16(a0[m], b0[n], acc[m][n], 0, 0, 0);
    __builtin_amdgcn_s_setprio(0);
    __builtin_amdgcn_s_barrier();

    // ---- phase 1: k-step 1 ----
    bf16x8 a1[4], b1[4];
    #pragma unroll
    for (int m = 0; m < 4; m++) a1[m] = rdA(buf, 1, m);
    #pragma unroll
    for (int n = 0; n < 4; n++) b1[n] = rdB(buf, 1, n);
    if (pf) { stB(buf ^ 1, kt + 1, 2); stB(buf ^ 1, kt + 1, 3); }
    __builtin_amdgcn_s_barrier();
    asm volatile("s_waitcnt lgkmcnt(0)" ::: "memory");
    __builtin_amdgcn_sched_barrier(0);
    __builtin_amdgcn_s_setprio(1);
    #pragma unroll
    for (int m = 0; m < 4; m++)
      #pragma unroll
      for (int n = 0; n < 4; n++)
        acc[m][n] = __builtin_amdgcn_mfma_f32_16x16x32_bf16(a1[m], b1[n], acc[m][n], 0, 0, 0);
    __builtin_amdgcn_s_setprio(0);
    __builtin_amdgcn_s_barrier();
  }

  // ---------------- epilogue ----------------
  if (MODE == 0) {
    const int which = col0 >> 10;   // block-uniform (1024 % 256 == 0)
    if (which == 2) {
      // V^T: vt[bh][dk][n]; 4 consecutive n pack to ushort4
      #pragma unroll
      for (int m = 0; m < 4; m++) {
        int row = row0 + wm * 64 + m * 16 + g * 4;
        int bb = row >> 10, nn = row & 1023;
        #pragma unroll
        for (int n = 0; n < 4; n++) {
          int col = col0 + wn * 64 + n * 16 + lr;
          int cc = col & 1023;
          int h = cc >> 6, dk = cc & 63;
          float bv = bias[col];
          ushort4 w;
          w.x = f2bf(acc[m][n][0] + bv);
          w.y = f2bf(acc[m][n][1] + bv);
          w.z = f2bf(acc[m][n][2] + bv);
          w.w = f2bf(acc[m][n][3] + bv);
          size_t idx = ((size_t)2 << 23) + (((size_t)(bb * 16 + h)) << 16) +
                       (size_t)dk * 1024 + nn;
          *(ushort4*)(qkv_out + idx) = w;
        }
      }
    } else {
      #pragma unroll
      for (int m = 0; m < 4; m++) {
        #pragma unroll
        for (int n = 0; n < 4; n++) {
          int col = col0 + wn * 64 + n * 16 + lr;
          int cc = col & 1023;
          int h = cc >> 6, dk = cc & 63;
          #pragma unroll
          for (int r = 0; r < 4; r++) {
            int row = row0 + wm * 64 + m * 16 + g * 4 + r;
            int bb = row >> 10, nn = row & 1023;
            float v = acc[m][n][r] + bias[col];
            if (which == 0) v *= 0.125f;   // fold 1/sqrt(dk) into Q
            size_t idx = ((size_t)which << 23) +
                         (((size_t)((bb * 16 + h) * 1024 + nn)) << 6) + dk;
            qkv_out[idx] = f2bf(v);
          }
        }
      }
    }
  } else {
    #pragma unroll
    for (int m = 0; m < 4; m++) {
      #pragma unroll
      for (int n = 0; n < 4; n++) {
        int col = col0 + wn * 64 + n * 16 + lr;
        #pragma unroll
        for (int r = 0; r < 4; r++) {
          int row = row0 + wm * 64 + m * 16 + g * 4 + r;
          Cout[(size_t)row * 1024 + col] = acc[m][n][r] + bias[col];
        }
      }
    }
  }
}

// ---------------------------------------------------------------------------
// Attention (unchanged from round 3): 8 waves, QBLK=128, KVBLK=64, dbuf
// prefetch, V pre-transposed by GEMM1, setprio, XCD swizzle.
// ---------------------------------------------------------------------------
__global__ __launch_bounds__(512) void attn_mfma(
    const unsigned short* __restrict__ qkv, unsigned short* __restrict__ attn_out) {
  __shared__ __align__(16) unsigned short K_lds[2][64 * 64];   // [k][d] swz
  __shared__ __align__(16) unsigned short V_lds[2][64 * 64];   // [d][k] swz
  __shared__ __align__(16) unsigned short P_lds[128 * 64];     // [q][k] swz

  const int bid = ((blockIdx.x & 7) << 7) + (blockIdx.x >> 3);
  const int bh = bid >> 3, qt = bid & 7;
  const unsigned short* Qp = qkv + ((size_t)bh << 16);
  const unsigned short* Kp = qkv + (1u << 23) + ((size_t)bh << 16);
  const unsigned short* Vt = qkv + (2u << 23) + ((size_t)bh << 16);  // [dk][n]

  const int t = threadIdx.x;
  const int lane = t & 63, wid = t >> 6;
  const int lr = lane & 15, g = lane >> 4;

  bf16x8 qf[2];
  {
    int qrow = qt * 128 + wid * 16 + lr;
    qf[0] = *(const bf16x8*)(Qp + (size_t)qrow * 64 + g * 8);
    qf[1] = *(const bf16x8*)(Qp + (size_t)qrow * 64 + 32 + g * 8);
  }

  const int srow = t >> 3;
  const int sch  = (t & 7) ^ (srow & 7);
  const int so   = t * 16;

  auto stage = [&](int buf, int kt) {
    GLOAD_LDS16(Kp + (size_t)(kt * 64 + srow) * 64 + sch * 8, (char*)&K_lds[buf][0] + so);
    GLOAD_LDS16(Vt + (size_t)srow * 1024 + kt * 64 + sch * 8, (char*)&V_lds[buf][0] + so);
  };

  f32x4 o_acc[4] = {};
  float den[4] = {0.f, 0.f, 0.f, 0.f};

  stage(0, 0);
  __syncthreads();
  int buf = 0;
  for (int kt = 0; kt < 16; kt++) {
    if (kt + 1 < 16) stage(buf ^ 1, kt + 1);

    f32x4 s4[4] = {};
    __builtin_amdgcn_s_setprio(1);
    #pragma unroll
    for (int ks = 0; ks < 4; ks++) {
      int krow = ks * 16 + lr;
      #pragma unroll
      for (int c = 0; c < 2; c++) {
        bf16x8 kf = *(const bf16x8*)((char*)&K_lds[buf][0] + krow * 128 +
                                     ((c * 64 + g * 16) ^ ((krow & 7) << 4)));
        s4[ks] = __builtin_amdgcn_mfma_f32_16x16x32_bf16(qf[c], kf, s4[ks], 0, 0, 0);
      }
    }
    __builtin_amdgcn_s_setprio(0);

    #pragma unroll
    for (int ks = 0; ks < 4; ks++) {
      #pragma unroll
      for (int r = 0; r < 4; r++) {
        float e = __expf(s4[ks][r]);
        den[r] += e;
        int q = wid * 16 + g * 4 + r;
        *(unsigned short*)((char*)P_lds + q * 128 +
                           (((ks * 16 + lr) * 2) ^ ((q & 7) << 4))) = f2bf(e);
      }
    }

    bf16x8 pa[2];
    {
      int q = wid * 16 + lr;
      #pragma unroll
      for (int c = 0; c < 2; c++)
        pa[c] = *(const bf16x8*)((char*)P_lds + q * 128 +
                                 ((c * 64 + g * 16) ^ ((q & 7) << 4)));
    }
    __builtin_amdgcn_s_setprio(1);
    #pragma unroll
    for (int ds_ = 0; ds_ < 4; ds_++) {
      int drow = ds_ * 16 + lr;
      #pragma unroll
      for (int c = 0; c < 2; c++) {
        bf16x8 vf = *(const bf16x8*)((char*)&V_lds[buf][0] + drow * 128 +
                                     ((c * 64 + g * 16) ^ ((drow & 7) << 4)));
        o_acc[ds_] = __builtin_amdgcn_mfma_f32_16x16x32_bf16(pa[c], vf, o_acc[ds_], 0, 0, 0);
      }
    }
    __builtin_amdgcn_s_setprio(0);
    __syncthreads();
    buf ^= 1;
  }

  #pragma unroll
  for (int r = 0; r < 4; r++) {
    den[r] += __shfl_xor(den[r], 1, 64);
    den[r] += __shfl_xor(den[r], 2, 64);
    den[r] += __shfl_xor(den[r], 4, 64);
    den[r] += __shfl_xor(den[r], 8, 64);
  }

  const int bb = bh >> 4, h = bh & 15;
  #pragma unroll
  for (int ds_ = 0; ds_ < 4; ds_++) {
    #pragma unroll
    for (int r = 0; r < 4; r++) {
      int q = qt * 128 + wid * 16 + g * 4 + r;
      int d = h * 64 + ds_ * 16 + lr;
      attn_out[((size_t)(bb * 1024 + q)) * 1024 + d] = f2bf(o_acc[ds_][r] / den[r]);
    }
  }
}

// ---------------------------------------------------------------------------
extern "C" void kernel_launch(void* const* d_in, const int* in_sizes, int n_in,
                              void* d_out, int out_size, void* d_ws, size_t ws_size,
                              hipStream_t stream) {
  const float* x     = (const float*)d_in[0];
  const float* W_qkv = (const float*)d_in[1];
  const float* b_qkv = (const float*)d_in[2];
  const float* W_o   = (const float*)d_in[3];
  const float* b_o   = (const float*)d_in[4];
  float* out = (float*)d_out;

  unsigned short* ws      = (unsigned short*)d_ws;
  unsigned short* x_bf    = ws;                     //  8388608
  unsigned short* wqkv_t  = x_bf + 8388608;         //  3145728
  unsigned short* wo_t    = wqkv_t + 3145728;       //  1048576
  unsigned short* qkv     = wo_t + 1048576;         // 25165824 (3 x 2^23)
  unsigned short* attn_o  = qkv + 25165824;         //  8388608

  cast_f32_to_bf16<<<2048, 256, 0, stream>>>(x, x_bf, 8388608 / 4);
  transpose_cast<<<dim3(96, 32), 256, 0, stream>>>(W_qkv, wqkv_t, 1024, 3072);
  transpose_cast<<<dim3(32, 32), 256, 0, stream>>>(W_o, wo_t, 1024, 1024);

  gemm256<0><<<dim3(12, 64), 512, 0, stream>>>(x_bf, wqkv_t, b_qkv, qkv, nullptr);
  attn_mfma<<<1024, 512, 0, stream>>>(qkv, attn_o);
  gemm256<1><<<dim3(4, 64), 512, 0, stream>>>(attn_o, wo_t, b_o, nullptr, out);
}

// Round 6
// 159.818 us; speedup vs baseline: 1.2043x; 1.1524x over previous
//
#include <hip/hip_runtime.h>

// MHSA fwd MFMA bf16: B=8, N=1024, D=1024, H=16, DK=64. fp32 in/out, bf16 compute.
// Round 6: GEMM 128x256 BK=64, 8 waves, 2x16-MFMA phases + TRIPLE-buffered LDS,
// 2-tile lookahead, vmcnt(6) counted waits (m201/m248 depth). Attention unchanged.

typedef __attribute__((ext_vector_type(8))) short bf16x8;
typedef __attribute__((ext_vector_type(4))) float f32x4;

#define GLOAD_LDS16(gp, lp)                                                              \
  __builtin_amdgcn_global_load_lds((const __attribute__((address_space(1))) void*)(gp),  \
                                   (__attribute__((address_space(3))) void*)(lp), 16, 0, 0)

__device__ __forceinline__ unsigned short f2bf(float f) {
  unsigned int u = __float_as_uint(f);
  u += 0x7fffu + ((u >> 16) & 1u);          // RNE
  return (unsigned short)(u >> 16);
}

// ---------------------------------------------------------------------------
__global__ __launch_bounds__(256) void cast_f32_to_bf16(
    const float* __restrict__ in, unsigned short* __restrict__ out, int n4) {
  int stride = gridDim.x * blockDim.x;
  for (int i = blockIdx.x * blockDim.x + threadIdx.x; i < n4; i += stride) {
    float4 v = reinterpret_cast<const float4*>(in)[i];
    ushort4 o;
    o.x = f2bf(v.x); o.y = f2bf(v.y); o.z = f2bf(v.z); o.w = f2bf(v.w);
    reinterpret_cast<ushort4*>(out)[i] = o;
  }
}

// W [R][C] f32 -> Wt [C][R] bf16
__global__ __launch_bounds__(256) void transpose_cast(
    const float* __restrict__ W, unsigned short* __restrict__ Wt, int R, int C) {
  __shared__ float tile[32][33];
  int tx = threadIdx.x & 31, ty = threadIdx.x >> 5;
  int c0 = blockIdx.x * 32, r0 = blockIdx.y * 32;
  #pragma unroll
  for (int i = 0; i < 4; i++) {
    int r = r0 + ty + i * 8;
    tile[ty + i * 8][tx] = W[(size_t)r * C + c0 + tx];
  }
  __syncthreads();
  #pragma unroll
  for (int i = 0; i < 4; i++) {
    int c = c0 + ty + i * 8;
    Wt[(size_t)c * R + r0 + tx] = f2bf(tile[tx][ty + i * 8]);
  }
}

// ---------------------------------------------------------------------------
// GEMM 128x256, BK=64, 512 thr (8 waves = 2M x 4N; 64x64 per wave, 4x4 frags).
// K=1024 -> 16 K-tiles. TRIPLE-buffered LDS; tile kt+2 staged during tile kt
// (3+3 loads across the 2 phases); tile-top wait vmcnt(6) keeps kt+1's loads
// in flight (drain only at kt=15). Per tile: 2 phases x 16 MFMA.
// MODE 0: qkv scatter (Q pre-scaled 0.125, V transposed per head). MODE 1: f32.
// ---------------------------------------------------------------------------
template <int MODE>
__global__ __launch_bounds__(512) void gemm256(
    const unsigned short* __restrict__ A, const unsigned short* __restrict__ Bt,
    const float* __restrict__ bias, unsigned short* __restrict__ qkv_out,
    float* __restrict__ Cout) {
  __shared__ __align__(16) unsigned short As[3][128 * 64];   // 48 KB, [row][k] swz
  __shared__ __align__(16) unsigned short Bs[3][256 * 64];   // 96 KB, [col][k] swz
  const int t = threadIdx.x;
  const int lane = t & 63, wid = t >> 6;
  const int lr = lane & 15, g = lane >> 4;
  const int wm = wid >> 2, wn = wid & 3;

  // XCD-aware bijective swizzle (grid counts divisible by 8)
  const int nwg = gridDim.x * gridDim.y;
  const int id = blockIdx.x + gridDim.x * blockIdx.y;
  const int sw = (id & 7) * (nwg >> 3) + (id >> 3);
  const int bx = sw % gridDim.x, by = sw / gridDim.x;
  const int row0 = by * 128, col0 = bx * 256;

  const int srow = t >> 3, sch = t & 7;     // staging: 512 thr x 16B = 64 rows

  auto stA = [&](int buf, int kt, int j) {  // j=0..1: rows j*64..j*64+63
    int row = j * 64 + srow;
    int ch = sch ^ (row & 7);               // source pre-swizzle
    GLOAD_LDS16(A + (size_t)(row0 + row) * 1024 + kt * 64 + ch * 8,
                (char*)&As[buf][0] + j * 8192 + t * 16);
  };
  auto stB = [&](int buf, int kt, int j) {  // j=0..3: cols j*64..j*64+63
    int row = j * 64 + srow;
    int ch = sch ^ (row & 7);
    GLOAD_LDS16(Bt + (size_t)(col0 + row) * 1024 + kt * 64 + ch * 8,
                (char*)&Bs[buf][0] + j * 8192 + t * 16);
  };
  auto rdA = [&](int buf, int c, int m) -> bf16x8 {
    int r = wm * 64 + m * 16 + lr;
    return *(const bf16x8*)((const char*)&As[buf][0] + r * 128 +
                            ((c * 64 + g * 16) ^ ((r & 7) << 4)));
  };
  auto rdB = [&](int buf, int c, int n) -> bf16x8 {
    int r = wn * 64 + n * 16 + lr;
    return *(const bf16x8*)((const char*)&Bs[buf][0] + r * 128 +
                            ((c * 64 + g * 16) ^ ((r & 7) << 4)));
  };

  f32x4 acc[4][4] = {};

  // prologue: stage tiles 0 and 1 (12 loads); wait for tile 0 only (6 in flight)
  stA(0, 0, 0); stA(0, 0, 1);
  stB(0, 0, 0); stB(0, 0, 1); stB(0, 0, 2); stB(0, 0, 3);
  stA(1, 1, 0); stA(1, 1, 1);
  stB(1, 1, 0); stB(1, 1, 1); stB(1, 1, 2); stB(1, 1, 3);
  asm volatile("s_waitcnt vmcnt(6)" ::: "memory");
  __builtin_amdgcn_s_barrier();

  for (int kt = 0; kt < 16; kt++) {
    const int buf = kt % 3;
    const int bufn = (kt + 2) % 3;
    const bool pf = (kt <= 13);
    if (kt > 0) {
      // own tile-kt loads are oldest; kt+1's 6 may stay in flight
      if (kt == 15) asm volatile("s_waitcnt vmcnt(0)" ::: "memory");
      else          asm volatile("s_waitcnt vmcnt(6)" ::: "memory");
      __builtin_amdgcn_s_barrier();
    }

    // ---- phase 0: k-step 0 ----
    bf16x8 a0[4], b0[4];
    #pragma unroll
    for (int m = 0; m < 4; m++) a0[m] = rdA(buf, 0, m);
    #pragma unroll
    for (int n = 0; n < 4; n++) b0[n] = rdB(buf, 0, n);
    if (pf) { stA(bufn, kt + 2, 0); stA(bufn, kt + 2, 1); stB(bufn, kt + 2, 0); }
    __builtin_amdgcn_s_barrier();
    asm volatile("s_waitcnt lgkmcnt(0)" ::: "memory");
    __builtin_amdgcn_sched_barrier(0);
    __builtin_amdgcn_s_setprio(1);
    #pragma unroll
    for (int m = 0; m < 4; m++)
      #pragma unroll
      for (int n = 0; n < 4; n++)
        acc[m][n] = __builtin_amdgcn_mfma_f32_16x16x32_bf16(a0[m], b0[n], acc[m][n], 0, 0, 0);
    __builtin_amdgcn_s_setprio(0);
    __builtin_amdgcn_s_barrier();

    // ---- phase 1: k-step 1 ----
    bf16x8 a1[4], b1[4];
    #pragma unroll
    for (int m = 0; m < 4; m++) a1[m] = rdA(buf, 1, m);
    #pragma unroll
    for (int n = 0; n < 4; n++) b1[n] = rdB(buf, 1, n);
    if (pf) { stB(bufn, kt + 2, 1); stB(bufn, kt + 2, 2); stB(bufn, kt + 2, 3); }
    __builtin_amdgcn_s_barrier();
    asm volatile("s_waitcnt lgkmcnt(0)" ::: "memory");
    __builtin_amdgcn_sched_barrier(0);
    __builtin_amdgcn_s_setprio(1);
    #pragma unroll
    for (int m = 0; m < 4; m++)
      #pragma unroll
      for (int n = 0; n < 4; n++)
        acc[m][n] = __builtin_amdgcn_mfma_f32_16x16x32_bf16(a1[m], b1[n], acc[m][n], 0, 0, 0);
    __builtin_amdgcn_s_setprio(0);
    __builtin_amdgcn_s_barrier();
  }

  // ---------------- epilogue ----------------
  if (MODE == 0) {
    const int which = col0 >> 10;   // block-uniform (1024 % 256 == 0)
    if (which == 2) {
      // V^T: vt[bh][dk][n]; 4 consecutive n pack to ushort4
      #pragma unroll
      for (int m = 0; m < 4; m++) {
        int row = row0 + wm * 64 + m * 16 + g * 4;
        int bb = row >> 10, nn = row & 1023;
        #pragma unroll
        for (int n = 0; n < 4; n++) {
          int col = col0 + wn * 64 + n * 16 + lr;
          int cc = col & 1023;
          int h = cc >> 6, dk = cc & 63;
          float bv = bias[col];
          ushort4 w;
          w.x = f2bf(acc[m][n][0] + bv);
          w.y = f2bf(acc[m][n][1] + bv);
          w.z = f2bf(acc[m][n][2] + bv);
          w.w = f2bf(acc[m][n][3] + bv);
          size_t idx = ((size_t)2 << 23) + (((size_t)(bb * 16 + h)) << 16) +
                       (size_t)dk * 1024 + nn;
          *(ushort4*)(qkv_out + idx) = w;
        }
      }
    } else {
      #pragma unroll
      for (int m = 0; m < 4; m++) {
        #pragma unroll
        for (int n = 0; n < 4; n++) {
          int col = col0 + wn * 64 + n * 16 + lr;
          int cc = col & 1023;
          int h = cc >> 6, dk = cc & 63;
          #pragma unroll
          for (int r = 0; r < 4; r++) {
            int row = row0 + wm * 64 + m * 16 + g * 4 + r;
            int bb = row >> 10, nn = row & 1023;
            float v = acc[m][n][r] + bias[col];
            if (which == 0) v *= 0.125f;   // fold 1/sqrt(dk) into Q
            size_t idx = ((size_t)which << 23) +
                         (((size_t)((bb * 16 + h) * 1024 + nn)) << 6) + dk;
            qkv_out[idx] = f2bf(v);
          }
        }
      }
    }
  } else {
    #pragma unroll
    for (int m = 0; m < 4; m++) {
      #pragma unroll
      for (int n = 0; n < 4; n++) {
        int col = col0 + wn * 64 + n * 16 + lr;
        #pragma unroll
        for (int r = 0; r < 4; r++) {
          int row = row0 + wm * 64 + m * 16 + g * 4 + r;
          Cout[(size_t)row * 1024 + col] = acc[m][n][r] + bias[col];
        }
      }
    }
  }
}

// ---------------------------------------------------------------------------
// Attention (unchanged from round 3): 8 waves, QBLK=128, KVBLK=64, dbuf
// prefetch, V pre-transposed by GEMM1, setprio, XCD swizzle.
// ---------------------------------------------------------------------------
__global__ __launch_bounds__(512) void attn_mfma(
    const unsigned short* __restrict__ qkv, unsigned short* __restrict__ attn_out) {
  __shared__ __align__(16) unsigned short K_lds[2][64 * 64];   // [k][d] swz
  __shared__ __align__(16) unsigned short V_lds[2][64 * 64];   // [d][k] swz
  __shared__ __align__(16) unsigned short P_lds[128 * 64];     // [q][k] swz

  const int bid = ((blockIdx.x & 7) << 7) + (blockIdx.x >> 3);
  const int bh = bid >> 3, qt = bid & 7;
  const unsigned short* Qp = qkv + ((size_t)bh << 16);
  const unsigned short* Kp = qkv + (1u << 23) + ((size_t)bh << 16);
  const unsigned short* Vt = qkv + (2u << 23) + ((size_t)bh << 16);  // [dk][n]

  const int t = threadIdx.x;
  const int lane = t & 63, wid = t >> 6;
  const int lr = lane & 15, g = lane >> 4;

  bf16x8 qf[2];
  {
    int qrow = qt * 128 + wid * 16 + lr;
    qf[0] = *(const bf16x8*)(Qp + (size_t)qrow * 64 + g * 8);
    qf[1] = *(const bf16x8*)(Qp + (size_t)qrow * 64 + 32 + g * 8);
  }

  const int srow = t >> 3;
  const int sch  = (t & 7) ^ (srow & 7);
  const int so   = t * 16;

  auto stage = [&](int buf, int kt) {
    GLOAD_LDS16(Kp + (size_t)(kt * 64 + srow) * 64 + sch * 8, (char*)&K_lds[buf][0] + so);
    GLOAD_LDS16(Vt + (size_t)srow * 1024 + kt * 64 + sch * 8, (char*)&V_lds[buf][0] + so);
  };

  f32x4 o_acc[4] = {};
  float den[4] = {0.f, 0.f, 0.f, 0.f};

  stage(0, 0);
  __syncthreads();
  int buf = 0;
  for (int kt = 0; kt < 16; kt++) {
    if (kt + 1 < 16) stage(buf ^ 1, kt + 1);

    f32x4 s4[4] = {};
    __builtin_amdgcn_s_setprio(1);
    #pragma unroll
    for (int ks = 0; ks < 4; ks++) {
      int krow = ks * 16 + lr;
      #pragma unroll
      for (int c = 0; c < 2; c++) {
        bf16x8 kf = *(const bf16x8*)((char*)&K_lds[buf][0] + krow * 128 +
                                     ((c * 64 + g * 16) ^ ((krow & 7) << 4)));
        s4[ks] = __builtin_amdgcn_mfma_f32_16x16x32_bf16(qf[c], kf, s4[ks], 0, 0, 0);
      }
    }
    __builtin_amdgcn_s_setprio(0);

    #pragma unroll
    for (int ks = 0; ks < 4; ks++) {
      #pragma unroll
      for (int r = 0; r < 4; r++) {
        float e = __expf(s4[ks][r]);
        den[r] += e;
        int q = wid * 16 + g * 4 + r;
        *(unsigned short*)((char*)P_lds + q * 128 +
                           (((ks * 16 + lr) * 2) ^ ((q & 7) << 4))) = f2bf(e);
      }
    }

    bf16x8 pa[2];
    {
      int q = wid * 16 + lr;
      #pragma unroll
      for (int c = 0; c < 2; c++)
        pa[c] = *(const bf16x8*)((char*)P_lds + q * 128 +
                                 ((c * 64 + g * 16) ^ ((q & 7) << 4)));
    }
    __builtin_amdgcn_s_setprio(1);
    #pragma unroll
    for (int ds_ = 0; ds_ < 4; ds_++) {
      int drow = ds_ * 16 + lr;
      #pragma unroll
      for (int c = 0; c < 2; c++) {
        bf16x8 vf = *(const bf16x8*)((char*)&V_lds[buf][0] + drow * 128 +
                                     ((c * 64 + g * 16) ^ ((drow & 7) << 4)));
        o_acc[ds_] = __builtin_amdgcn_mfma_f32_16x16x32_bf16(pa[c], vf, o_acc[ds_], 0, 0, 0);
      }
    }
    __builtin_amdgcn_s_setprio(0);
    __syncthreads();
    buf ^= 1;
  }

  #pragma unroll
  for (int r = 0; r < 4; r++) {
    den[r] += __shfl_xor(den[r], 1, 64);
    den[r] += __shfl_xor(den[r], 2, 64);
    den[r] += __shfl_xor(den[r], 4, 64);
    den[r] += __shfl_xor(den[r], 8, 64);
  }

  const int bb = bh >> 4, h = bh & 15;
  #pragma unroll
  for (int ds_ = 0; ds_ < 4; ds_++) {
    #pragma unroll
    for (int r = 0; r < 4; r++) {
      int q = qt * 128 + wid * 16 + g * 4 + r;
      int d = h * 64 + ds_ * 16 + lr;
      attn_out[((size_t)(bb * 1024 + q)) * 1024 + d] = f2bf(o_acc[ds_][r] / den[r]);
    }
  }
}

// ---------------------------------------------------------------------------
extern "C" void kernel_launch(void* const* d_in, const int* in_sizes, int n_in,
                              void* d_out, int out_size, void* d_ws, size_t ws_size,
                              hipStream_t stream) {
  const float* x     = (const float*)d_in[0];
  const float* W_qkv = (const float*)d_in[1];
  const float* b_qkv = (const float*)d_in[2];
  const float* W_o   = (const float*)d_in[3];
  const float* b_o   = (const float*)d_in[4];
  float* out = (float*)d_out;

  unsigned short* ws      = (unsigned short*)d_ws;
  unsigned short* x_bf    = ws;                     //  8388608
  unsigned short* wqkv_t  = x_bf + 8388608;         //  3145728
  unsigned short* wo_t    = wqkv_t + 3145728;       //  1048576
  unsigned short* qkv     = wo_t + 1048576;         // 25165824 (3 x 2^23)
  unsigned short* attn_o  = qkv + 25165824;         //  8388608

  cast_f32_to_bf16<<<2048, 256, 0, stream>>>(x, x_bf, 8388608 / 4);
  transpose_cast<<<dim3(96, 32), 256, 0, stream>>>(W_qkv, wqkv_t, 1024, 3072);
  transpose_cast<<<dim3(32, 32), 256, 0, stream>>>(W_o, wo_t, 1024, 1024);

  gemm256<0><<<dim3(12, 64), 512, 0, stream>>>(x_bf, wqkv_t, b_qkv, qkv, nullptr);
  attn_mfma<<<1024, 512, 0, stream>>>(qkv, attn_o);
  gemm256<1><<<dim3(4, 64), 512, 0, stream>>>(attn_o, wo_t, b_o, nullptr, out);
}